// Round 2
// baseline (682.820 us; speedup 1.0000x reference)
//
#include <hip/hip_runtime.h>
#include <hip/hip_fp16.h>

typedef _Float16 half_t;
typedef __attribute__((ext_vector_type(4))) _Float16 f16x4;
typedef __attribute__((ext_vector_type(8))) _Float16 f16x8;
typedef __attribute__((ext_vector_type(4))) float f32x4;

#define WAVES_PER_BLOCK 16
#define MAIN_BLOCK 1024
#define MAIN_GRID 512

// ---------------------------------------------------------------------------
// Prep: z (fp32, [N_NODES,128]) -> zh (f16, row-contiguous, for A gathers)
// ---------------------------------------------------------------------------
__global__ void prep_z_kernel(const float* __restrict__ z,
                              half_t* __restrict__ zh, int n4) {
    int t = blockIdx.x * 256 + threadIdx.x;
    if (t < n4) {
        const float4 v = reinterpret_cast<const float4*>(z)[t];
        f16x4 o;
        o[0] = (_Float16)v.x; o[1] = (_Float16)v.y;
        o[2] = (_Float16)v.z; o[3] = (_Float16)v.w;
        reinterpret_cast<f16x4*>(zh)[t] = o;
    }
}

// ---------------------------------------------------------------------------
// Main: each wave computes a 32-edge x 128-H tile.
//   W1 converted fp32->f16 and swizzled into MFMA B-fragment order in LDS
//   once per block (no workspace needed).
//   B-fragment (ks, nt): lane L, elem j holds
//     W1[k = ks*32 + (L>>4)*8 + j][n = nt*16 + (L&15)]
//   flat f16 LDS index = ((ks*8 + nt)*64 + L)*8 + j  -> one ds_read_b128
//   per fragment, consecutive lanes = consecutive 16B (conflict-free).
//   A (gathered z rows) -> VGPR directly from global.
//   Epilogue: bias + relu + dot(W2) fused, quad shfl_xor reduction.
// ---------------------------------------------------------------------------
template <bool F16Z>
__global__ __launch_bounds__(MAIN_BLOCK, 4)
void edge_mlp_kernel(const float* __restrict__ z,
                     const half_t* __restrict__ zh,
                     const int* __restrict__ eidx,
                     const float* __restrict__ W1,
                     const float* __restrict__ b1,
                     const float* __restrict__ W2,
                     const float* __restrict__ b2,
                     float* __restrict__ out,
                     int n_edges, int n_groups, int stride_groups) {
    __shared__ __align__(16) half_t w1_lds[32768];   // 64 KB
    // Stage + swizzle W1: coalesced fp32 reads, scattered f16 LDS writes.
#pragma unroll
    for (int i = 0; i < 32; ++i) {
        const int u = threadIdx.x + i * MAIN_BLOCK;  // flat k*128+n, 0..32767
        const int k = u >> 7, n = u & 127;
        const int t = (((k >> 5) * 8 + (n >> 4)) * 64 +
                       ((k >> 3) & 3) * 16 + (n & 15)) * 8 + (k & 7);
        w1_lds[t] = (half_t)W1[u];
    }
    __syncthreads();

    const int wave = threadIdx.x >> 6;
    const int lane = threadIdx.x & 63;
    const int nlo  = lane & 15;
    const int quad = lane >> 4;

    float b1v[8], w2v[8];
#pragma unroll
    for (int nt = 0; nt < 8; ++nt) {
        b1v[nt] = b1[nt * 16 + nlo];
        w2v[nt] = W2[nt * 16 + nlo];
    }
    const float b2v = b2[0];

    const f16x8* blds = reinterpret_cast<const f16x8*>(w1_lds);

    for (int g = blockIdx.x * WAVES_PER_BLOCK + wave; g < n_groups;
         g += stride_groups) {
        const int e0 = g * 32;
        int em0 = e0 + nlo;           // edge giving A row m = nlo, M-tile 0
        int em1 = e0 + 16 + nlo;      // M-tile 1
        if (em0 >= n_edges) em0 = n_edges - 1;
        if (em1 >= n_edges) em1 = n_edges - 1;
        const int s0 = eidx[em0];
        const int s1 = eidx[em1];
        const int d0 = eidx[n_edges + em0];
        const int d1 = eidx[n_edges + em1];

        f32x4 acc[2][8];
#pragma unroll
        for (int mt = 0; mt < 2; ++mt)
#pragma unroll
            for (int nt = 0; nt < 8; ++nt)
                acc[mt][nt] = (f32x4){0.f, 0.f, 0.f, 0.f};

#pragma unroll
        for (int ks = 0; ks < 8; ++ks) {
            const int koff = (ks & 3) * 32 + quad * 8;  // k offset in z row
            const int r0 = (ks < 4) ? s0 : d0;
            const int r1 = (ks < 4) ? s1 : d1;
            f16x8 a0, a1;
            if (F16Z) {
                a0 = *reinterpret_cast<const f16x8*>(zh + (size_t)r0 * 128 + koff);
                a1 = *reinterpret_cast<const f16x8*>(zh + (size_t)r1 * 128 + koff);
            } else {
                const float4* p0 =
                    reinterpret_cast<const float4*>(z + (size_t)r0 * 128 + koff);
                const float4* p1 =
                    reinterpret_cast<const float4*>(z + (size_t)r1 * 128 + koff);
                const float4 v0a = p0[0], v0b = p0[1];
                const float4 v1a = p1[0], v1b = p1[1];
                a0[0] = (_Float16)v0a.x; a0[1] = (_Float16)v0a.y;
                a0[2] = (_Float16)v0a.z; a0[3] = (_Float16)v0a.w;
                a0[4] = (_Float16)v0b.x; a0[5] = (_Float16)v0b.y;
                a0[6] = (_Float16)v0b.z; a0[7] = (_Float16)v0b.w;
                a1[0] = (_Float16)v1a.x; a1[1] = (_Float16)v1a.y;
                a1[2] = (_Float16)v1a.z; a1[3] = (_Float16)v1a.w;
                a1[4] = (_Float16)v1b.x; a1[5] = (_Float16)v1b.y;
                a1[6] = (_Float16)v1b.z; a1[7] = (_Float16)v1b.w;
            }
            const f16x8* bp = blds + ks * 512 + lane;
#pragma unroll
            for (int nt = 0; nt < 8; ++nt) {
                const f16x8 bf = bp[nt * 64];
                acc[0][nt] = __builtin_amdgcn_mfma_f32_16x16x32_f16(
                    a0, bf, acc[0][nt], 0, 0, 0);
                acc[1][nt] = __builtin_amdgcn_mfma_f32_16x16x32_f16(
                    a1, bf, acc[1][nt], 0, 0, 0);
            }
        }

        // Epilogue: out[e] = b2 + sum_n relu(h[e][n] + b1[n]) * W2[n]
        // C/D layout: n = nt*16 + (lane&15), m = mt*16 + quad*4 + r.
#pragma unroll
        for (int mt = 0; mt < 2; ++mt) {
#pragma unroll
            for (int r = 0; r < 4; ++r) {
                float s = 0.f;
#pragma unroll
                for (int nt = 0; nt < 8; ++nt) {
                    const float h = acc[mt][nt][r] + b1v[nt];
                    s = fmaf(fmaxf(h, 0.f), w2v[nt], s);
                }
                // reduce over the 16 lanes of this quad (n mod 16 slices)
                s += __shfl_xor(s, 1);
                s += __shfl_xor(s, 2);
                s += __shfl_xor(s, 4);
                s += __shfl_xor(s, 8);
                const int e = e0 + mt * 16 + quad * 4 + r;
                if (nlo == mt * 4 + r && e < n_edges)
                    out[e] = s + b2v;
            }
        }
    }
}

extern "C" void kernel_launch(void* const* d_in, const int* in_sizes, int n_in,
                              void* d_out, int out_size, void* d_ws,
                              size_t ws_size, hipStream_t stream) {
    const float* z   = (const float*)d_in[0];
    const int* eidx  = (const int*)d_in[1];   // harness passes int64 ref as int32
    const float* W1  = (const float*)d_in[2];
    const float* b1  = (const float*)d_in[3];
    const float* W2  = (const float*)d_in[4];
    const float* b2  = (const float*)d_in[5];
    float* out       = (float*)d_out;

    const int nz      = in_sizes[0];      // 12,800,000 (N_NODES*128)
    const int n_edges = in_sizes[1] / 2;  // 1,000,000

    const int n_groups = (n_edges + 31) / 32;
    const int stride_groups = MAIN_GRID * WAVES_PER_BLOCK;

    const size_t zh_bytes = (size_t)nz * sizeof(half_t);
    if (ws_size >= zh_bytes) {
        half_t* zh = (half_t*)d_ws;
        const int n4 = nz / 4;
        prep_z_kernel<<<(n4 + 255) / 256, 256, 0, stream>>>(z, zh, n4);
        edge_mlp_kernel<true><<<MAIN_GRID, MAIN_BLOCK, 0, stream>>>(
            z, zh, eidx, W1, b1, W2, b2, out, n_edges, n_groups, stride_groups);
    } else {
        edge_mlp_kernel<false><<<MAIN_GRID, MAIN_BLOCK, 0, stream>>>(
            z, nullptr, eidx, W1, b1, W2, b2, out, n_edges, n_groups,
            stride_groups);
    }
}